// Round 1
// baseline (1352.162 us; speedup 1.0000x reference)
//
#include <hip/hip_runtime.h>
#include <hip/hip_bf16.h>

#define N_NODES 50000
#define E_EDGES 600000
#define HDIM    128

// monotonic float<->uint encoding for atomicMax on floats
__device__ __forceinline__ unsigned fenc(float f) {
    unsigned u = __float_as_uint(f);
    return (u & 0x80000000u) ? ~u : (u | 0x80000000u);
}
__device__ __forceinline__ float fdec(unsigned v) {
    unsigned u = (v & 0x80000000u) ? (v ^ 0x80000000u) : ~v;
    return __uint_as_float(u);
}

// ---- Phase 1: Q = x Wq^T + bq, K = x Wk^T + bk, V = x Wv^T + bv ----
// 256 threads/block, 16 rows of x per block. x tile staged in LDS
// (broadcast reads), W rows streamed per-thread (L1/L2 resident, 64 KB each).
__global__ __launch_bounds__(256) void qkv_kernel(
    const float* __restrict__ x,
    const float* __restrict__ Wq, const float* __restrict__ bq,
    const float* __restrict__ Wk, const float* __restrict__ bk,
    const float* __restrict__ Wv, const float* __restrict__ bv,
    float* __restrict__ Q, float* __restrict__ K, float* __restrict__ V)
{
    __shared__ float xs[16][HDIM];
    const int r0 = blockIdx.x * 16;
    {
        const float4* src = (const float4*)(x + (size_t)r0 * HDIM);
        float4* dst = (float4*)&xs[0][0];
        for (int i = threadIdx.x; i < 16 * HDIM / 4; i += 256) dst[i] = src[i];
    }
    __syncthreads();
    const int c  = threadIdx.x & 127;   // output column 0..127
    const int rh = threadIdx.x >> 7;    // row half: 0 or 1
    float aq[8], ak[8], av[8];
#pragma unroll
    for (int i = 0; i < 8; ++i) { aq[i] = 0.f; ak[i] = 0.f; av[i] = 0.f; }
    const float4* wq4 = (const float4*)(Wq + (size_t)c * HDIM);
    const float4* wk4 = (const float4*)(Wk + (size_t)c * HDIM);
    const float4* wv4 = (const float4*)(Wv + (size_t)c * HDIM);
    for (int h = 0; h < HDIM / 4; ++h) {
        float4 wq = wq4[h], wk = wk4[h], wv = wv4[h];
#pragma unroll
        for (int i = 0; i < 8; ++i) {
            const int r = rh * 8 + i;
            float4 xv = *(const float4*)&xs[r][h * 4];
            aq[i] += xv.x * wq.x + xv.y * wq.y + xv.z * wq.z + xv.w * wq.w;
            ak[i] += xv.x * wk.x + xv.y * wk.y + xv.z * wk.z + xv.w * wk.w;
            av[i] += xv.x * wv.x + xv.y * wv.y + xv.z * wv.z + xv.w * wv.w;
        }
    }
    const float bqc = bq[c], bkc = bk[c], bvc = bv[c];
#pragma unroll
    for (int i = 0; i < 8; ++i) {
        const size_t r = (size_t)(r0 + rh * 8 + i);
        Q[r * HDIM + c] = aq[i] + bqc;
        K[r * HDIM + c] = ak[i] + bkc;
        V[r * HDIM + c] = av[i] + bvc;
    }
}

// ---- Phase 2: per-edge energy + global max ----
// 32 lanes per edge; each lane loads a float4 of Q[row] and K[col].
__global__ __launch_bounds__(256) void energy_kernel(
    const float* __restrict__ Q, const float* __restrict__ K,
    const int* __restrict__ ei, const float* __restrict__ ew,
    float* __restrict__ energy, unsigned* __restrict__ gmax)
{
    const int gid     = blockIdx.x * 256 + threadIdx.x;
    const int lane    = gid & 31;
    const int group   = gid >> 5;
    const int ngroups = (gridDim.x * 256) >> 5;
    const float inv_scale = 0.08838834764831845f;  // 1/sqrt(128)
    float lmax = -3.4e38f;
    for (int e = group; e < E_EDGES; e += ngroups) {
        const int row = ei[e];
        const int col = ei[E_EDGES + e];
        float4 q = *(const float4*)&Q[(size_t)row * HDIM + lane * 4];
        float4 k = *(const float4*)&K[(size_t)col * HDIM + lane * 4];
        float d = q.x * k.x + q.y * k.y + q.z * k.z + q.w * k.w;
#pragma unroll
        for (int m = 16; m >= 1; m >>= 1) d += __shfl_xor(d, m);
        const float en = d * inv_scale * ew[e];
        if (lane == 0) energy[e] = en;
        lmax = fmaxf(lmax, en);
    }
#pragma unroll
    for (int m = 32; m >= 1; m >>= 1) lmax = fmaxf(lmax, __shfl_xor(lmax, m));
    __shared__ float sm[4];
    if ((threadIdx.x & 63) == 0) sm[threadIdx.x >> 6] = lmax;
    __syncthreads();
    if (threadIdx.x == 0) {
        float m = fmaxf(fmaxf(sm[0], sm[1]), fmaxf(sm[2], sm[3]));
        atomicMax(gmax, fenc(m));
    }
}

// ---- Phase 3: p[e] = exp(energy - gmax), gsum = sum p ----
__global__ __launch_bounds__(256) void expsum_kernel(
    float* __restrict__ energy, const unsigned* __restrict__ gmax,
    float* __restrict__ gsum)
{
    const float m = fdec(*gmax);
    const int gid  = blockIdx.x * 256 + threadIdx.x;
    const int nthr = gridDim.x * 256;
    float lsum = 0.f;
    for (int e = gid; e < E_EDGES; e += nthr) {
        float p = __expf(energy[e] - m);
        energy[e] = p;
        lsum += p;
    }
#pragma unroll
    for (int mm = 32; mm >= 1; mm >>= 1) lsum += __shfl_xor(lsum, mm);
    __shared__ float sm[4];
    if ((threadIdx.x & 63) == 0) sm[threadIdx.x >> 6] = lsum;
    __syncthreads();
    if (threadIdx.x == 0) atomicAdd(gsum, sm[0] + sm[1] + sm[2] + sm[3]);
}

// ---- Phase 4: out[row] += V[col] * (p[e]/gsum) via HW f32 atomics ----
__global__ __launch_bounds__(256) void scatter_kernel(
    const float* __restrict__ V, const float* __restrict__ p,
    const int* __restrict__ ei, const float* __restrict__ gsum,
    float* __restrict__ out)
{
    const float inv = 1.0f / *gsum;
    const int gid   = blockIdx.x * 256 + threadIdx.x;
    const int lane  = gid & 31;
    const int group = gid >> 5;
    if (group >= E_EDGES) return;
    const int row = ei[group];
    const int col = ei[E_EDGES + group];
    const float w = p[group] * inv;
    float4 v = *(const float4*)&V[(size_t)col * HDIM + lane * 4];
    float* o = out + (size_t)row * HDIM + lane * 4;
    unsafeAtomicAdd(o + 0, v.x * w);
    unsafeAtomicAdd(o + 1, v.y * w);
    unsafeAtomicAdd(o + 2, v.z * w);
    unsafeAtomicAdd(o + 3, v.w * w);
}

extern "C" void kernel_launch(void* const* d_in, const int* in_sizes, int n_in,
                              void* d_out, int out_size, void* d_ws, size_t ws_size,
                              hipStream_t stream)
{
    const float* x  = (const float*)d_in[0];
    const int*   ei = (const int*)d_in[1];
    const float* ew = (const float*)d_in[2];
    const float* Wq = (const float*)d_in[3];
    const float* bq = (const float*)d_in[4];
    const float* Wk = (const float*)d_in[5];
    const float* bk = (const float*)d_in[6];
    const float* Wv = (const float*)d_in[7];
    const float* bv = (const float*)d_in[8];
    float* out = (float*)d_out;

    char* ws = (char*)d_ws;
    float* Q      = (float*)ws;                       // N*H floats
    float* K      = Q + (size_t)N_NODES * HDIM;       // N*H
    float* V      = K + (size_t)N_NODES * HDIM;       // N*H
    float* energy = V + (size_t)N_NODES * HDIM;       // E
    unsigned* gmax = (unsigned*)(energy + E_EDGES);   // 1
    float*    gsum = (float*)(gmax + 1);              // 1

    hipMemsetAsync(d_out, 0, (size_t)out_size * sizeof(float), stream);
    hipMemsetAsync(gmax, 0, 8, stream);  // gmax -> encoded -inf-ish, gsum -> 0

    qkv_kernel<<<N_NODES / 16, 256, 0, stream>>>(x, Wq, bq, Wk, bk, Wv, bv, Q, K, V);
    energy_kernel<<<4096, 256, 0, stream>>>(Q, K, ei, ew, energy, gmax);
    expsum_kernel<<<2048, 256, 0, stream>>>(energy, gmax, gsum);
    scatter_kernel<<<(E_EDGES * 32) / 256, 256, 0, stream>>>(V, energy, ei, gsum, out);
}

// Round 2
// 453.995 us; speedup vs baseline: 2.9784x; 2.9784x over previous
//
#include <hip/hip_runtime.h>
#include <hip/hip_bf16.h>

#define N_NODES 50000
#define E_EDGES 600000
#define HDIM    128

#define QKV_BLOCKS  (N_NODES / 16)            // 3125
#define EDGE_BLOCKS ((E_EDGES + 255) / 256)   // 2344
#define SCAN_BLOCKS ((N_NODES + 255) / 256)   // 196
#define ROW_BLOCKS  (N_NODES / 4)             // 12500 (4 waves/block, 1 wave/row)

// ---- Phase 1: Q = x Wq^T + bq, K = x Wk^T + bk, V = x Wv^T + bv ----
__global__ __launch_bounds__(256) void qkv_kernel(
    const float* __restrict__ x,
    const float* __restrict__ Wq, const float* __restrict__ bq,
    const float* __restrict__ Wk, const float* __restrict__ bk,
    const float* __restrict__ Wv, const float* __restrict__ bv,
    float* __restrict__ Q, float* __restrict__ K, float* __restrict__ V)
{
    __shared__ float xs[16][HDIM];
    const int r0 = blockIdx.x * 16;
    {
        const float4* src = (const float4*)(x + (size_t)r0 * HDIM);
        float4* dst = (float4*)&xs[0][0];
        for (int i = threadIdx.x; i < 16 * HDIM / 4; i += 256) dst[i] = src[i];
    }
    __syncthreads();
    const int c  = threadIdx.x & 127;
    const int rh = threadIdx.x >> 7;
    float aq[8], ak[8], av[8];
#pragma unroll
    for (int i = 0; i < 8; ++i) { aq[i] = 0.f; ak[i] = 0.f; av[i] = 0.f; }
    const float4* wq4 = (const float4*)(Wq + (size_t)c * HDIM);
    const float4* wk4 = (const float4*)(Wk + (size_t)c * HDIM);
    const float4* wv4 = (const float4*)(Wv + (size_t)c * HDIM);
    for (int h = 0; h < HDIM / 4; ++h) {
        float4 wq = wq4[h], wk = wk4[h], wv = wv4[h];
#pragma unroll
        for (int i = 0; i < 8; ++i) {
            const int r = rh * 8 + i;
            float4 xv = *(const float4*)&xs[r][h * 4];
            aq[i] += xv.x * wq.x + xv.y * wq.y + xv.z * wq.z + xv.w * wq.w;
            ak[i] += xv.x * wk.x + xv.y * wk.y + xv.z * wk.z + xv.w * wk.w;
            av[i] += xv.x * wv.x + xv.y * wv.y + xv.z * wv.z + xv.w * wv.w;
        }
    }
    const float bqc = bq[c], bkc = bk[c], bvc = bv[c];
#pragma unroll
    for (int i = 0; i < 8; ++i) {
        const size_t r = (size_t)(r0 + rh * 8 + i);
        Q[r * HDIM + c] = aq[i] + bqc;
        K[r * HDIM + c] = ak[i] + bkc;
        V[r * HDIM + c] = av[i] + bvc;
    }
}

// ---- Phase 2a: histogram of destination rows ----
__global__ __launch_bounds__(256) void hist_kernel(
    const int* __restrict__ ei, int* __restrict__ counts)
{
    const int e = blockIdx.x * 256 + threadIdx.x;
    if (e < E_EDGES) atomicAdd(&counts[ei[e]], 1);
}

// ---- Phase 2b: exclusive prefix scan (3 small kernels) ----
__global__ __launch_bounds__(256) void scan_partial_kernel(
    const int* __restrict__ counts, int* __restrict__ offs, int* __restrict__ aux)
{
    __shared__ int s[256];
    const int i = blockIdx.x * 256 + threadIdx.x;
    const int v = (i < N_NODES) ? counts[i] : 0;
    s[threadIdx.x] = v;
    __syncthreads();
    for (int d = 1; d < 256; d <<= 1) {
        int t = (threadIdx.x >= d) ? s[threadIdx.x - d] : 0;
        __syncthreads();
        s[threadIdx.x] += t;
        __syncthreads();
    }
    if (i < N_NODES) offs[i] = s[threadIdx.x] - v;   // exclusive within block
    if (threadIdx.x == 255) aux[blockIdx.x] = s[255];
}

__global__ __launch_bounds__(256) void scan_aux_kernel(int* __restrict__ aux)
{
    __shared__ int s[256];
    const int i = threadIdx.x;
    const int v = (i < SCAN_BLOCKS) ? aux[i] : 0;
    s[i] = v;
    __syncthreads();
    for (int d = 1; d < 256; d <<= 1) {
        int t = (i >= d) ? s[i - d] : 0;
        __syncthreads();
        s[i] += t;
        __syncthreads();
    }
    if (i < SCAN_BLOCKS) aux[i] = s[i] - v;          // exclusive
}

__global__ __launch_bounds__(256) void scan_add_kernel(
    int* __restrict__ offs, const int* __restrict__ aux, int* __restrict__ cursor)
{
    const int i = blockIdx.x * 256 + threadIdx.x;
    if (i < N_NODES) {
        const int o = offs[i] + aux[blockIdx.x];
        offs[i] = o;
        cursor[i] = o;
    }
}

// ---- Phase 2c: bin edges by destination row ----
__global__ __launch_bounds__(256) void bin_kernel(
    const int* __restrict__ ei, const float* __restrict__ ew,
    int* __restrict__ cursor, int* __restrict__ bcol, float* __restrict__ bew)
{
    const int e = blockIdx.x * 256 + threadIdx.x;
    if (e >= E_EDGES) return;
    const int row = ei[e];
    const int pos = atomicAdd(&cursor[row], 1);
    bcol[pos] = ei[E_EDGES + e];
    bew[pos]  = ew[e];
}

// ---- Phase 3: per-edge energy (one wave per row, Q row cached in regs) ----
__global__ __launch_bounds__(256) void energy_kernel(
    const float* __restrict__ Q, const float* __restrict__ K,
    const int* __restrict__ offs, const int* __restrict__ counts,
    const int* __restrict__ bcol, const float* __restrict__ bew,
    float* __restrict__ bp, float* __restrict__ blockmax)
{
    const int row  = (blockIdx.x * 256 + threadIdx.x) >> 6;
    const int lane = threadIdx.x & 63;
    const int start = offs[row], len = counts[row];
    const float2 q = *(const float2*)&Q[(size_t)row * HDIM + lane * 2];
    const float inv_scale = 0.08838834764831845f;  // 1/sqrt(128)
    float lmax = -3.4e38f;
    for (int j = 0; j < len; ++j) {
        const int   c = bcol[start + j];
        const float w = bew[start + j];
        float2 k = *(const float2*)&K[(size_t)c * HDIM + lane * 2];
        float d = q.x * k.x + q.y * k.y;
#pragma unroll
        for (int m = 32; m >= 1; m >>= 1) d += __shfl_xor(d, m);
        const float en = d * inv_scale * w;
        if (lane == 0) bp[start + j] = en;
        lmax = fmaxf(lmax, en);
    }
    __shared__ float sm[4];
    if (lane == 0) sm[threadIdx.x >> 6] = lmax;
    __syncthreads();
    if (threadIdx.x == 0)
        blockmax[blockIdx.x] = fmaxf(fmaxf(sm[0], sm[1]), fmaxf(sm[2], sm[3]));
}

__global__ __launch_bounds__(256) void reduce_max_kernel(
    const float* __restrict__ bm, int n, float* __restrict__ gmax)
{
    float m = -3.4e38f;
    for (int i = threadIdx.x; i < n; i += 256) m = fmaxf(m, bm[i]);
#pragma unroll
    for (int s = 32; s >= 1; s >>= 1) m = fmaxf(m, __shfl_xor(m, s));
    __shared__ float sm[4];
    if ((threadIdx.x & 63) == 0) sm[threadIdx.x >> 6] = m;
    __syncthreads();
    if (threadIdx.x == 0) *gmax = fmaxf(fmaxf(sm[0], sm[1]), fmaxf(sm[2], sm[3]));
}

// ---- Phase 4: p = exp(en - max), partial sums ----
__global__ __launch_bounds__(256) void expsum_kernel(
    float* __restrict__ bp, const float* __restrict__ gmax,
    float* __restrict__ blocksum)
{
    const float m = *gmax;
    const int e = blockIdx.x * 256 + threadIdx.x;
    float p = 0.f;
    if (e < E_EDGES) { p = __expf(bp[e] - m); bp[e] = p; }
#pragma unroll
    for (int s = 32; s >= 1; s >>= 1) p += __shfl_xor(p, s);
    __shared__ float sm[4];
    if ((threadIdx.x & 63) == 0) sm[threadIdx.x >> 6] = p;
    __syncthreads();
    if (threadIdx.x == 0) blocksum[blockIdx.x] = sm[0] + sm[1] + sm[2] + sm[3];
}

__global__ __launch_bounds__(256) void reduce_sum_kernel(
    const float* __restrict__ bs, int n, float* __restrict__ gsum)
{
    float v = 0.f;
    for (int i = threadIdx.x; i < n; i += 256) v += bs[i];
#pragma unroll
    for (int s = 32; s >= 1; s >>= 1) v += __shfl_xor(v, s);
    __shared__ float sm[4];
    if ((threadIdx.x & 63) == 0) sm[threadIdx.x >> 6] = v;
    __syncthreads();
    if (threadIdx.x == 0) *gsum = sm[0] + sm[1] + sm[2] + sm[3];
}

// ---- Phase 5: out[row] = sum_j V[bcol[j]] * p[j] / gsum  (no atomics) ----
__global__ __launch_bounds__(256) void accum_kernel(
    const float* __restrict__ V,
    const int* __restrict__ offs, const int* __restrict__ counts,
    const int* __restrict__ bcol, const float* __restrict__ bp,
    const float* __restrict__ gsum, float* __restrict__ out)
{
    const int row  = (blockIdx.x * 256 + threadIdx.x) >> 6;
    const int lane = threadIdx.x & 63;
    const float inv = 1.0f / *gsum;
    const int start = offs[row], len = counts[row];
    float ax = 0.f, ay = 0.f;
    for (int j = 0; j < len; ++j) {
        const int   c = bcol[start + j];
        const float w = bp[start + j] * inv;
        float2 v = *(const float2*)&V[(size_t)c * HDIM + lane * 2];
        ax += v.x * w;
        ay += v.y * w;
    }
    *(float2*)&out[(size_t)row * HDIM + lane * 2] = make_float2(ax, ay);
}

extern "C" void kernel_launch(void* const* d_in, const int* in_sizes, int n_in,
                              void* d_out, int out_size, void* d_ws, size_t ws_size,
                              hipStream_t stream)
{
    const float* x  = (const float*)d_in[0];
    const int*   ei = (const int*)d_in[1];
    const float* ew = (const float*)d_in[2];
    const float* Wq = (const float*)d_in[3];
    const float* bq = (const float*)d_in[4];
    const float* Wk = (const float*)d_in[5];
    const float* bk = (const float*)d_in[6];
    const float* Wv = (const float*)d_in[7];
    const float* bv = (const float*)d_in[8];
    float* out = (float*)d_out;

    float* ws = (float*)d_ws;
    float* Q       = ws;                                  // N*H
    float* K       = Q + (size_t)N_NODES * HDIM;          // N*H
    float* V       = K + (size_t)N_NODES * HDIM;          // N*H
    float* fp      = V + (size_t)N_NODES * HDIM;
    int*   counts  = (int*)fp;                            // N
    int*   offs    = counts + N_NODES;                    // N
    int*   cursor  = offs + N_NODES;                      // N
    int*   aux     = cursor + N_NODES;                    // SCAN_BLOCKS
    int*   bcol    = aux + 256;                           // E
    float* bew     = (float*)(bcol + E_EDGES);            // E
    float* bp      = bew + E_EDGES;                       // E
    float* blockmax= bp + E_EDGES;                        // ROW_BLOCKS
    float* blocksum= blockmax + ROW_BLOCKS;               // EDGE_BLOCKS
    float* gmax    = blocksum + EDGE_BLOCKS;              // 1
    float* gsum    = gmax + 1;                            // 1

    hipMemsetAsync(counts, 0, N_NODES * sizeof(int), stream);

    qkv_kernel<<<QKV_BLOCKS, 256, 0, stream>>>(x, Wq, bq, Wk, bk, Wv, bv, Q, K, V);
    hist_kernel<<<EDGE_BLOCKS, 256, 0, stream>>>(ei, counts);
    scan_partial_kernel<<<SCAN_BLOCKS, 256, 0, stream>>>(counts, offs, aux);
    scan_aux_kernel<<<1, 256, 0, stream>>>(aux);
    scan_add_kernel<<<SCAN_BLOCKS, 256, 0, stream>>>(offs, aux, cursor);
    bin_kernel<<<EDGE_BLOCKS, 256, 0, stream>>>(ei, ew, cursor, bcol, bew);
    energy_kernel<<<ROW_BLOCKS, 256, 0, stream>>>(Q, K, offs, counts, bcol, bew, bp, blockmax);
    reduce_max_kernel<<<1, 256, 0, stream>>>(blockmax, ROW_BLOCKS, gmax);
    expsum_kernel<<<EDGE_BLOCKS, 256, 0, stream>>>(bp, gmax, blocksum);
    reduce_sum_kernel<<<1, 256, 0, stream>>>(blocksum, EDGE_BLOCKS, gsum);
    accum_kernel<<<ROW_BLOCKS, 256, 0, stream>>>(V, offs, counts, bcol, bp, gsum, out);
}